// Round 1
// baseline (772.206 us; speedup 1.0000x reference)
//
#include <hip/hip_runtime.h>
#include <math.h>

// Problem constants (from reference)
#define DD   16     // model dim
#define NH   8      // heads (head dim = 2)
#define NL   8      // layers
#define FFD  16     // ff dim
#define KK   35     // conv kernel / patch size
#define SEQ  3500   // input seq
#define NP   100    // patches
#define SS   101    // tokens (cls + patches)
#define NT   128    // threads per block (2 waves); thread s owns row s
#define KVSTR 33    // kv row stride in LDS (+1 pad: bank = (s+e)%32, conflict-free writes)

__device__ __forceinline__ void lnorm16(float* h, const float* __restrict__ g,
                                        const float* __restrict__ bb) {
  float mu = 0.f;
  #pragma unroll
  for (int d = 0; d < DD; ++d) mu += h[d];
  mu *= (1.f / DD);
  float var = 0.f;
  #pragma unroll
  for (int d = 0; d < DD; ++d) { float c = h[d] - mu; var += c * c; }
  var *= (1.f / DD);
  const float r = rsqrtf(var + 1e-5f);
  #pragma unroll
  for (int d = 0; d < DD; ++d) h[d] = (h[d] - mu) * r * g[d] + bb[d];
}

__global__ __launch_bounds__(NT)
void transformer_fwd(const float* __restrict__ x,
                     const float* __restrict__ conv_w,  const float* __restrict__ conv_b,
                     const float* __restrict__ cls_emb,
                     const float* __restrict__ Wqkv,    const float* __restrict__ bqkv,
                     const float* __restrict__ Wo,      const float* __restrict__ bo,
                     const float* __restrict__ W1,      const float* __restrict__ b1,
                     const float* __restrict__ W2,      const float* __restrict__ b2,
                     const float* __restrict__ ln1_g,   const float* __restrict__ ln1_b,
                     const float* __restrict__ ln2_g,   const float* __restrict__ ln2_b,
                     const float* __restrict__ lnf_g,   const float* __restrict__ lnf_b,
                     const float* __restrict__ end_w,   const float* __restrict__ end_b,
                     const float* __restrict__ head_w,  const float* __restrict__ head_b,
                     float* __restrict__ out)
{
  // s_buf: first the coalesced x stage (3500 f), then reused as kv[SS][KVSTR]
  // (k in cols 0..15, v in cols 16..31; 101*33 = 3333 <= 3500).
  __shared__ float s_buf[SEQ];
  __shared__ float s_cls[DD];
  __shared__ float s_lat[NP];

  const int b   = blockIdx.x;
  const int tid = threadIdx.x;
  const bool act = (tid < SS);

  // ---- stage x coalesced ----
  const float* xrow = x + (size_t)b * SEQ;
  for (int i = tid; i < SEQ; i += NT) s_buf[i] = xrow[i];
  __syncthreads();

  // ---- conv patch embed (thread s -> row s) ----
  float h[DD];
  if (tid == 0) {
    #pragma unroll
    for (int d = 0; d < DD; ++d) h[d] = cls_emb[d];
  } else if (act) {
    float xv[KK];
    const int base = (tid - 1) * KK;
    #pragma unroll
    for (int k = 0; k < KK; ++k) xv[k] = s_buf[base + k];
    #pragma unroll
    for (int f = 0; f < DD; ++f) {
      float acc = conv_b[f];                 // uniform -> s_load
      #pragma unroll
      for (int k = 0; k < KK; ++k) acc += xv[k] * conv_w[f * KK + k];
      h[f] = acc;
    }
  }

  const float scale = 0.70710678118654752f;  // 1/sqrt(head_dim=2)

  for (int l = 0; l < NL; ++l) {
    const float* wq  = Wqkv + l * (3 * DD * DD);
    const float* bq  = bqkv + l * (3 * DD);
    const float* wo  = Wo   + l * (DD * DD);
    const float* bol = bo   + l * DD;
    const float* w1  = W1   + l * (FFD * DD);
    const float* b1l = b1   + l * FFD;
    const float* w2  = W2   + l * (DD * FFD);
    const float* b2l = b2   + l * DD;
    const float* g1  = ln1_g + l * DD;  const float* be1 = ln1_b + l * DD;
    const float* g2  = ln2_g + l * DD;  const float* be2 = ln2_b + l * DD;

    // all prior reads of s_buf (x stage / previous attention) complete
    __syncthreads();

    float q[DD];
    if (act) {
      // qkv = h @ Wqkv^T + b; q stays in registers, k/v go to LDS
      #pragma unroll
      for (int e = 0; e < 3 * DD; ++e) {
        float acc = bq[e];                   // uniform -> s_load
        #pragma unroll
        for (int d = 0; d < DD; ++d) acc += h[d] * wq[e * DD + d];
        if (e < DD) q[e] = acc;
        else        s_buf[tid * KVSTR + (e - DD)] = acc;
      }
    }
    __syncthreads();

    if (act) {
      // ---- attention: single-pass softmax (scores are tiny; no overflow) ----
      float lsum[NH];
      float ctx[DD];
      #pragma unroll
      for (int hh = 0; hh < NH; ++hh) lsum[hh] = 0.f;
      #pragma unroll
      for (int d = 0; d < DD; ++d) ctx[d] = 0.f;

      for (int t = 0; t < SS; ++t) {
        const float* kv = &s_buf[t * KVSTR]; // uniform address -> LDS broadcast
        #pragma unroll
        for (int hh = 0; hh < NH; ++hh) {
          const float sc = (q[2*hh] * kv[2*hh] + q[2*hh + 1] * kv[2*hh + 1]) * scale;
          const float p  = __expf(sc);
          lsum[hh]     += p;
          ctx[2*hh]     += p * kv[DD + 2*hh];
          ctx[2*hh + 1] += p * kv[DD + 2*hh + 1];
        }
      }
      #pragma unroll
      for (int hh = 0; hh < NH; ++hh) {
        const float inv = 1.f / lsum[hh];
        ctx[2*hh] *= inv;  ctx[2*hh + 1] *= inv;
      }

      // ---- Wo + residual + LN1 ----
      float o[DD];
      #pragma unroll
      for (int od = 0; od < DD; ++od) {
        float acc = bol[od];
        #pragma unroll
        for (int d = 0; d < DD; ++d) acc += ctx[d] * wo[od * DD + d];
        o[od] = acc;
      }
      #pragma unroll
      for (int d = 0; d < DD; ++d) h[d] += o[d];
      lnorm16(h, g1, be1);

      // ---- FF + residual + LN2 ----
      float fv[FFD];
      #pragma unroll
      for (int f = 0; f < FFD; ++f) {
        float acc = b1l[f];
        #pragma unroll
        for (int d = 0; d < DD; ++d) acc += h[d] * w1[f * DD + d];
        fv[f] = fmaxf(acc, 0.f);
      }
      #pragma unroll
      for (int od = 0; od < DD; ++od) {
        float acc = b2l[od];
        #pragma unroll
        for (int f = 0; f < FFD; ++f) acc += fv[f] * w2[od * FFD + f];
        h[od] += acc;
      }
      lnorm16(h, g2, be2);
    }
  }

  // ---- final LN (cls row only) + head ----
  if (tid == 0) {
    lnorm16(h, lnf_g, lnf_b);
    #pragma unroll
    for (int d = 0; d < DD; ++d) s_cls[d] = h[d];
  }
  __syncthreads();
  if (tid < NP) {
    float acc = end_b[tid];
    #pragma unroll
    for (int d = 0; d < DD; ++d) acc += s_cls[d] * end_w[tid * DD + d];
    s_lat[tid] = acc * head_w[tid];           // fold head matvec weight in
  }
  __syncthreads();
  if (tid == 0) {
    float acc = head_b[0];
    for (int j = 0; j < NP; ++j) acc += s_lat[j];
    out[b] = 1.f / (1.f + __expf(-acc));
  }
}

extern "C" void kernel_launch(void* const* d_in, const int* in_sizes, int n_in,
                              void* d_out, int out_size, void* d_ws, size_t ws_size,
                              hipStream_t stream) {
  const float* x       = (const float*)d_in[0];
  const float* conv_w  = (const float*)d_in[1];
  const float* conv_b  = (const float*)d_in[2];
  const float* cls_emb = (const float*)d_in[3];
  const float* Wqkv    = (const float*)d_in[4];
  const float* bqkv    = (const float*)d_in[5];
  const float* Wo      = (const float*)d_in[6];
  const float* bo      = (const float*)d_in[7];
  const float* W1      = (const float*)d_in[8];
  const float* b1      = (const float*)d_in[9];
  const float* W2      = (const float*)d_in[10];
  const float* b2      = (const float*)d_in[11];
  const float* ln1_g   = (const float*)d_in[12];
  const float* ln1_b   = (const float*)d_in[13];
  const float* ln2_g   = (const float*)d_in[14];
  const float* ln2_b   = (const float*)d_in[15];
  const float* lnf_g   = (const float*)d_in[16];
  const float* lnf_b   = (const float*)d_in[17];
  const float* end_w   = (const float*)d_in[18];
  const float* end_b   = (const float*)d_in[19];
  const float* head_w  = (const float*)d_in[20];
  const float* head_b  = (const float*)d_in[21];
  float* out = (float*)d_out;

  const int B = in_sizes[0] / SEQ;   // 2048
  transformer_fwd<<<B, NT, 0, stream>>>(
      x, conv_w, conv_b, cls_emb, Wqkv, bqkv, Wo, bo, W1, b1, W2, b2,
      ln1_g, ln1_b, ln2_g, ln2_b, lnf_g, lnf_b, end_w, end_b, head_w, head_b,
      out);
}

// Round 2
// 677.562 us; speedup vs baseline: 1.1397x; 1.1397x over previous
//
#include <hip/hip_runtime.h>
#include <math.h>

// Problem constants
#define DD   16     // model dim
#define NH   8      // heads (head dim = 2)
#define NL   8      // layers
#define FFD  16     // ff dim
#define KK   35     // conv kernel / patch size
#define SEQ  3500   // input seq
#define NP   100    // patches
#define SS   101    // tokens (cls + patches)
#define NBATCH 3    // batch elements per block (303/320 lanes active = 95%)
#define NT   320    // 5 waves
#define KROW 8      // half2 (dword) units per row in s_K  (16 halves)
#define VROW 8      // float2 units per row in s_V         (16 floats)
#define KREG (SS*KROW + 4)   // 812 dwords / region (pad keeps cross-region banks offset)
#define VREG (SS*VROW + 2)   // 810 float2 / region

typedef __fp16 h2 __attribute__((ext_vector_type(2)));
typedef float  f2 __attribute__((ext_vector_type(2)));

__device__ __forceinline__ float fdot2(h2 a, h2 b, float c) {
#if __has_builtin(__builtin_amdgcn_fdot2)
  return __builtin_amdgcn_fdot2(a, b, c, false);
#else
  return c + (float)a.x * (float)b.x + (float)a.y * (float)b.y;
#endif
}

__device__ __forceinline__ float exp2_fast(float x) {
#if __has_builtin(__builtin_amdgcn_exp2f)
  return __builtin_amdgcn_exp2f(x);
#else
  return exp2f(x);
#endif
}

__device__ __forceinline__ float rcp_fast(float x) {
#if __has_builtin(__builtin_amdgcn_rcpf)
  return __builtin_amdgcn_rcpf(x);
#else
  return 1.0f / x;
#endif
}

__device__ __forceinline__ h2 pk_h2(float a, float b) {
#if __has_builtin(__builtin_amdgcn_cvt_pkrtz)
  return __builtin_amdgcn_cvt_pkrtz(a, b);
#else
  h2 r; r.x = (__fp16)a; r.y = (__fp16)b; return r;
#endif
}

__device__ __forceinline__ void lnorm16(float* h, const float* __restrict__ g,
                                        const float* __restrict__ bb) {
  float mu = 0.f;
  #pragma unroll
  for (int d = 0; d < DD; ++d) mu += h[d];
  mu *= (1.f / DD);
  float var = 0.f;
  #pragma unroll
  for (int d = 0; d < DD; ++d) { float c = h[d] - mu; var += c * c; }
  var *= (1.f / DD);
  const float r = rsqrtf(var + 1e-5f);
  #pragma unroll
  for (int d = 0; d < DD; ++d) h[d] = (h[d] - mu) * r * g[d] + bb[d];
}

__global__ __launch_bounds__(NT)
void transformer_fwd(const float* __restrict__ x,
                     const float* __restrict__ conv_w,  const float* __restrict__ conv_b,
                     const float* __restrict__ cls_emb,
                     const float* __restrict__ Wqkv,    const float* __restrict__ bqkv,
                     const float* __restrict__ Wo,      const float* __restrict__ bo,
                     const float* __restrict__ W1,      const float* __restrict__ b1,
                     const float* __restrict__ W2,      const float* __restrict__ b2,
                     const float* __restrict__ ln1_g,   const float* __restrict__ ln1_b,
                     const float* __restrict__ ln2_g,   const float* __restrict__ ln2_b,
                     const float* __restrict__ lnf_g,   const float* __restrict__ lnf_b,
                     const float* __restrict__ end_w,   const float* __restrict__ end_b,
                     const float* __restrict__ head_w,  const float* __restrict__ head_b,
                     float* __restrict__ out, int B)
{
  __shared__ h2    s_K[NBATCH][KREG];   // k in fp16 pairs (one half2 per head)
  __shared__ f2    s_V[NBATCH][VREG];   // v in fp32 pairs (one float2 per head)
  __shared__ float s_cls[NBATCH][DD];
  __shared__ float s_lat[NBATCH][NP];

  const int tid = threadIdx.x;
  const int j   = tid / SS;           // batch slot (valid only when act)
  const int r   = tid - j * SS;       // row within batch
  const int b   = blockIdx.x * NBATCH + j;
  const bool act = (tid < NBATCH * SS) && (b < B);

  // ---- conv patch embed (direct global reads; x traffic is ~5 µs, irrelevant) ----
  float h[DD];
  if (act) {
    if (r == 0) {
      #pragma unroll
      for (int d = 0; d < DD; ++d) h[d] = cls_emb[d];
    } else {
      const float* xp = x + (size_t)b * SEQ + (r - 1) * KK;
      float xv[KK];
      #pragma unroll
      for (int k = 0; k < KK; ++k) xv[k] = xp[k];
      #pragma unroll
      for (int f = 0; f < DD; ++f) {
        float acc = conv_b[f];                 // uniform -> s_load
        #pragma unroll
        for (int k = 0; k < KK; ++k) acc += xv[k] * conv_w[f * KK + k];
        h[f] = acc;
      }
    }
  }

  // fold attn scale (1/sqrt(2)) and log2(e) into q before fp16 conversion
  const float qs = 1.4426950408889634f * 0.70710678118654752f;

  for (int l = 0; l < NL; ++l) {
    const float* wq  = Wqkv + l * (3 * DD * DD);
    const float* bq  = bqkv + l * (3 * DD);
    const float* wo  = Wo   + l * (DD * DD);
    const float* bol = bo   + l * DD;
    const float* w1  = W1   + l * (FFD * DD);
    const float* b1l = b1   + l * FFD;
    const float* w2  = W2   + l * (DD * FFD);
    const float* b2l = b2   + l * DD;
    const float* g1  = ln1_g + l * DD;  const float* be1 = ln1_b + l * DD;
    const float* g2  = ln2_g + l * DD;  const float* be2 = ln2_b + l * DD;

    __syncthreads();   // prior t-loop reads of s_K/s_V complete

    h2 q2[NH];
    if (act) {
      // q (pre-scaled, fp16 pairs)
      #pragma unroll
      for (int hh = 0; hh < NH; ++hh) {
        const int e0 = 2 * hh;
        float a0 = bq[e0], a1 = bq[e0 + 1];
        #pragma unroll
        for (int d = 0; d < DD; ++d) {
          a0 += h[d] * wq[e0 * DD + d];
          a1 += h[d] * wq[(e0 + 1) * DD + d];
        }
        q2[hh] = pk_h2(a0 * qs, a1 * qs);
      }
      // k -> LDS fp16 pairs
      h2* kw = &s_K[j][r * KROW];
      #pragma unroll
      for (int hh = 0; hh < NH; ++hh) {
        const int e0 = DD + 2 * hh;
        float a0 = bq[e0], a1 = bq[e0 + 1];
        #pragma unroll
        for (int d = 0; d < DD; ++d) {
          a0 += h[d] * wq[e0 * DD + d];
          a1 += h[d] * wq[(e0 + 1) * DD + d];
        }
        kw[hh] = pk_h2(a0, a1);
      }
      // v -> LDS fp32 pairs
      f2* vw = &s_V[j][r * VROW];
      #pragma unroll
      for (int hh = 0; hh < NH; ++hh) {
        const int e0 = 2 * DD + 2 * hh;
        float a0 = bq[e0], a1 = bq[e0 + 1];
        #pragma unroll
        for (int d = 0; d < DD; ++d) {
          a0 += h[d] * wq[e0 * DD + d];
          a1 += h[d] * wq[(e0 + 1) * DD + d];
        }
        f2 vv; vv.x = a0; vv.y = a1;
        vw[hh] = vv;
      }
    }
    __syncthreads();

    if (act) {
      // ---- attention: single-pass softmax, fdot2 + exp2 + pk_fma inner ----
      float lsum[NH];
      f2 ctx[NH];
      #pragma unroll
      for (int hh = 0; hh < NH; ++hh) { lsum[hh] = 0.f; ctx[hh].x = 0.f; ctx[hh].y = 0.f; }

      const h2* kp0 = &s_K[j][0];
      const f2* vp0 = &s_V[j][0];
      for (int t = 0; t < SS; ++t) {
        const h2* kp = kp0 + t * KROW;
        const f2* vp = vp0 + t * VROW;
        #pragma unroll
        for (int hh = 0; hh < NH; ++hh) {
          const float p = exp2_fast(fdot2(q2[hh], kp[hh], 0.0f));
          lsum[hh] += p;
          ctx[hh]  += vp[hh] * p;      // v_pk_fma_f32
        }
      }

      float cx[DD];
      #pragma unroll
      for (int hh = 0; hh < NH; ++hh) {
        const float inv = rcp_fast(lsum[hh]);
        cx[2 * hh]     = ctx[hh].x * inv;
        cx[2 * hh + 1] = ctx[hh].y * inv;
      }

      // ---- Wo + residual + LN1 ----
      #pragma unroll
      for (int od = 0; od < DD; ++od) {
        float acc = bol[od];
        #pragma unroll
        for (int d = 0; d < DD; ++d) acc += cx[d] * wo[od * DD + d];
        h[od] += acc;
      }
      lnorm16(h, g1, be1);

      // ---- FF + residual + LN2 ----
      float fv[FFD];
      #pragma unroll
      for (int f = 0; f < FFD; ++f) {
        float acc = b1l[f];
        #pragma unroll
        for (int d = 0; d < DD; ++d) acc += h[d] * w1[f * DD + d];
        fv[f] = fmaxf(acc, 0.f);
      }
      #pragma unroll
      for (int od = 0; od < DD; ++od) {
        float acc = b2l[od];
        #pragma unroll
        for (int f = 0; f < FFD; ++f) acc += fv[f] * w2[od * FFD + f];
        h[od] += acc;
      }
      lnorm16(h, g2, be2);
    }
  }

  // ---- final LN (cls rows) + head ----
  __syncthreads();
  if (act && r == 0) {
    lnorm16(h, lnf_g, lnf_b);
    #pragma unroll
    for (int d = 0; d < DD; ++d) s_cls[j][d] = h[d];
  }
  __syncthreads();
  if (tid < NBATCH * NP) {
    const int jj = tid / NP;
    const int oo = tid - jj * NP;
    if (blockIdx.x * NBATCH + jj < B) {
      float acc = end_b[oo];
      #pragma unroll
      for (int d = 0; d < DD; ++d) acc += s_cls[jj][d] * end_w[oo * DD + d];
      s_lat[jj][oo] = acc * head_w[oo];   // fold head matvec weight in
    }
  }
  __syncthreads();
  if (tid < NBATCH) {
    const int bb = blockIdx.x * NBATCH + tid;
    if (bb < B) {
      float acc = head_b[0];
      for (int o = 0; o < NP; ++o) acc += s_lat[tid][o];
      out[bb] = rcp_fast(1.f + exp2_fast(-acc * 1.4426950408889634f));
    }
  }
}

extern "C" void kernel_launch(void* const* d_in, const int* in_sizes, int n_in,
                              void* d_out, int out_size, void* d_ws, size_t ws_size,
                              hipStream_t stream) {
  const float* x       = (const float*)d_in[0];
  const float* conv_w  = (const float*)d_in[1];
  const float* conv_b  = (const float*)d_in[2];
  const float* cls_emb = (const float*)d_in[3];
  const float* Wqkv    = (const float*)d_in[4];
  const float* bqkv    = (const float*)d_in[5];
  const float* Wo      = (const float*)d_in[6];
  const float* bo      = (const float*)d_in[7];
  const float* W1      = (const float*)d_in[8];
  const float* b1      = (const float*)d_in[9];
  const float* W2      = (const float*)d_in[10];
  const float* b2      = (const float*)d_in[11];
  const float* ln1_g   = (const float*)d_in[12];
  const float* ln1_b   = (const float*)d_in[13];
  const float* ln2_g   = (const float*)d_in[14];
  const float* ln2_b   = (const float*)d_in[15];
  const float* lnf_g   = (const float*)d_in[16];
  const float* lnf_b   = (const float*)d_in[17];
  const float* end_w   = (const float*)d_in[18];
  const float* end_b   = (const float*)d_in[19];
  const float* head_w  = (const float*)d_in[20];
  const float* head_b  = (const float*)d_in[21];
  float* out = (float*)d_out;

  const int B  = in_sizes[0] / SEQ;                    // 2048
  const int nb = (B + NBATCH - 1) / NBATCH;            // 683
  transformer_fwd<<<nb, NT, 0, stream>>>(
      x, conv_w, conv_b, cls_emb, Wqkv, bqkv, Wo, bo, W1, b1, W2, b2,
      ln1_g, ln1_b, ln2_g, ln2_b, lnf_g, lnf_b, end_w, end_b, head_w, head_b,
      out, B);
}

// Round 3
// 631.541 us; speedup vs baseline: 1.2227x; 1.0729x over previous
//
#include <hip/hip_runtime.h>
#include <math.h>

// Problem constants
#define DD   16     // model dim
#define NH   8      // heads (head dim = 2)
#define NL   8      // layers
#define FFD  16     // ff dim
#define KK   35     // conv kernel / patch size
#define SEQ  3500   // input seq
#define NP   100    // patches
#define SS   101    // tokens (cls + patches)
#define NBATCH 2    // batches per block
#define NT   256    // 4 waves; grid = 1024 = exactly 4 blocks/CU
#define ROWB 64     // bytes per kv row in workspace (32 B fp16 K + 32 B fp16 V)
#define BATB (SS * ROWB)   // 6464 B per batch kv region

typedef __fp16 h2 __attribute__((ext_vector_type(2)));

__device__ __forceinline__ float fdot2(h2 a, h2 b, float c) {
#if __has_builtin(__builtin_amdgcn_fdot2)
  return __builtin_amdgcn_fdot2(a, b, c, false);
#else
  return c + (float)a.x * (float)b.x + (float)a.y * (float)b.y;
#endif
}
__device__ __forceinline__ float exp2_fast(float x) {
#if __has_builtin(__builtin_amdgcn_exp2f)
  return __builtin_amdgcn_exp2f(x);
#else
  return exp2f(x);
#endif
}
__device__ __forceinline__ float rcp_fast(float x) {
#if __has_builtin(__builtin_amdgcn_rcpf)
  return __builtin_amdgcn_rcpf(x);
#else
  return 1.0f / x;
#endif
}
__device__ __forceinline__ h2 pk_h2(float a, float b) {
#if __has_builtin(__builtin_amdgcn_cvt_pkrtz)
  return __builtin_amdgcn_cvt_pkrtz(a, b);
#else
  h2 r; r.x = (__fp16)a; r.y = (__fp16)b; return r;
#endif
}
__device__ __forceinline__ unsigned pk_u(float a, float b) {
  return __builtin_bit_cast(unsigned, pk_h2(a, b));
}
__device__ __forceinline__ h2 as_h2(unsigned u) {
  return __builtin_bit_cast(h2, u);
}

__device__ __forceinline__ void lnorm16(float* h, const float* __restrict__ g,
                                        const float* __restrict__ bb) {
  float mu = 0.f;
  #pragma unroll
  for (int d = 0; d < DD; ++d) mu += h[d];
  mu *= (1.f / DD);
  float var = 0.f;
  #pragma unroll
  for (int d = 0; d < DD; ++d) { float c = h[d] - mu; var += c * c; }
  var *= (1.f / DD);
  const float r = rsqrtf(var + 1e-5f);
  #pragma unroll
  for (int d = 0; d < DD; ++d) h[d] = (h[d] - mu) * r * g[d] + bb[d];
}

// ---------------- primary kernel: kv via global (wave-uniform broadcast loads) ----
__global__ __launch_bounds__(NT)
void transformer_fwd_g(const float* __restrict__ x,
                       const float* __restrict__ conv_w,  const float* __restrict__ conv_b,
                       const float* __restrict__ cls_emb,
                       const float* __restrict__ Wqkv,    const float* __restrict__ bqkv,
                       const float* __restrict__ Wo,      const float* __restrict__ bo,
                       const float* __restrict__ W1,      const float* __restrict__ b1,
                       const float* __restrict__ W2,      const float* __restrict__ b2,
                       const float* __restrict__ ln1_g,   const float* __restrict__ ln1_b,
                       const float* __restrict__ ln2_g,   const float* __restrict__ ln2_b,
                       const float* __restrict__ lnf_g,   const float* __restrict__ lnf_b,
                       const float* __restrict__ end_w,   const float* __restrict__ end_b,
                       const float* __restrict__ head_w,  const float* __restrict__ head_b,
                       float* __restrict__ out, char* __restrict__ ws, int B)
{
  __shared__ float s_cls[NBATCH][DD];
  __shared__ float s_lat[NBATCH][NP];

  const int tid = threadIdx.x;
  const int j   = tid / SS;           // batch slot within block
  const int r   = tid - j * SS;       // row
  const int b   = blockIdx.x * NBATCH + j;
  const bool act = (tid < NBATCH * SS) && (b < B);

  // per-batch kv region in workspace
  uint4* kvreg = (uint4*)(ws + (size_t)b * BATB);

  // ---- conv patch embed ----
  float h[DD];
  if (act) {
    if (r == 0) {
      #pragma unroll
      for (int d = 0; d < DD; ++d) h[d] = cls_emb[d];
    } else {
      const float* xp = x + (size_t)b * SEQ + (r - 1) * KK;
      float xv[KK];
      #pragma unroll
      for (int k = 0; k < KK; ++k) xv[k] = xp[k];
      #pragma unroll
      for (int f = 0; f < DD; ++f) {
        float acc = conv_b[f];
        #pragma unroll
        for (int k = 0; k < KK; ++k) acc += xv[k] * conv_w[f * KK + k];
        h[f] = acc;
      }
    }
  }

  // fold attn scale (1/sqrt(2)) and log2(e) into q before fp16 conversion
  const float qs = 1.4426950408889634f * 0.70710678118654752f;

  for (int l = 0; l < NL; ++l) {
    const float* wq  = Wqkv + l * (3 * DD * DD);
    const float* bq  = bqkv + l * (3 * DD);
    const float* wo  = Wo   + l * (DD * DD);
    const float* bol = bo   + l * DD;
    const float* w1  = W1   + l * (FFD * DD);
    const float* b1l = b1   + l * FFD;
    const float* w2  = W2   + l * (DD * FFD);
    const float* b2l = b2   + l * DD;
    const float* g1  = ln1_g + l * DD;  const float* be1 = ln1_b + l * DD;
    const float* g2  = ln2_g + l * DD;  const float* be2 = ln2_b + l * DD;

    __syncthreads();   // prior t-loop reads of kv region complete

    h2 q2[NH];
    if (act) {
      // q (pre-scaled fp16 pairs)
      #pragma unroll
      for (int hh = 0; hh < NH; ++hh) {
        const int e0 = 2 * hh;
        float a0 = bq[e0], a1 = bq[e0 + 1];
        #pragma unroll
        for (int d = 0; d < DD; ++d) {
          a0 += h[d] * wq[e0 * DD + d];
          a1 += h[d] * wq[(e0 + 1) * DD + d];
        }
        q2[hh] = pk_h2(a0 * qs, a1 * qs);
      }
      // k, v -> fp16 packed row (64 B) in global ws
      unsigned row[16];
      #pragma unroll
      for (int hh = 0; hh < NH; ++hh) {
        const int e0 = DD + 2 * hh;
        float a0 = bq[e0], a1 = bq[e0 + 1];
        #pragma unroll
        for (int d = 0; d < DD; ++d) {
          a0 += h[d] * wq[e0 * DD + d];
          a1 += h[d] * wq[(e0 + 1) * DD + d];
        }
        row[hh] = pk_u(a0, a1);
      }
      #pragma unroll
      for (int hh = 0; hh < NH; ++hh) {
        const int e0 = 2 * DD + 2 * hh;
        float a0 = bq[e0], a1 = bq[e0 + 1];
        #pragma unroll
        for (int d = 0; d < DD; ++d) {
          a0 += h[d] * wq[e0 * DD + d];
          a1 += h[d] * wq[(e0 + 1) * DD + d];
        }
        row[8 + hh] = pk_u(a0, a1);
      }
      uint4* dst = kvreg + (size_t)r * 4;
      dst[0] = make_uint4(row[0],  row[1],  row[2],  row[3]);
      dst[1] = make_uint4(row[4],  row[5],  row[6],  row[7]);
      dst[2] = make_uint4(row[8],  row[9],  row[10], row[11]);
      dst[3] = make_uint4(row[12], row[13], row[14], row[15]);
    }
    __syncthreads();   // kv visible block-wide (global writes drain before barrier)

    if (act) {
      // ---- attention: wave-uniform global kv loads (L1 broadcast), fp32 ctx ----
      float lsum[NH], cxx[NH], cxy[NH];
      #pragma unroll
      for (int hh = 0; hh < NH; ++hh) { lsum[hh] = 0.f; cxx[hh] = 0.f; cxy[hh] = 0.f; }

      #pragma unroll 2
      for (int t = 0; t < SS; ++t) {
        const uint4 ka = kvreg[4 * t + 0];
        const uint4 kb = kvreg[4 * t + 1];
        const uint4 va = kvreg[4 * t + 2];
        const uint4 vb = kvreg[4 * t + 3];
        const unsigned ku[8] = {ka.x, ka.y, ka.z, ka.w, kb.x, kb.y, kb.z, kb.w};
        const unsigned vu[8] = {va.x, va.y, va.z, va.w, vb.x, vb.y, vb.z, vb.w};
        #pragma unroll
        for (int hh = 0; hh < NH; ++hh) {
          const h2 kk = as_h2(ku[hh]);
          const h2 vv = as_h2(vu[hh]);
          const float p = exp2_fast(fdot2(q2[hh], kk, 0.0f));
          lsum[hh] += p;
          cxx[hh]  += (float)vv.x * p;   // v_fma_mix
          cxy[hh]  += (float)vv.y * p;
        }
      }

      float cx[DD];
      #pragma unroll
      for (int hh = 0; hh < NH; ++hh) {
        const float inv = rcp_fast(lsum[hh]);
        cx[2 * hh]     = cxx[hh] * inv;
        cx[2 * hh + 1] = cxy[hh] * inv;
      }

      // ---- Wo + residual + LN1 ----
      #pragma unroll
      for (int od = 0; od < DD; ++od) {
        float acc = bol[od];
        #pragma unroll
        for (int d = 0; d < DD; ++d) acc += cx[d] * wo[od * DD + d];
        h[od] += acc;
      }
      lnorm16(h, g1, be1);

      // ---- FF + residual + LN2 ----
      float fv[FFD];
      #pragma unroll
      for (int f = 0; f < FFD; ++f) {
        float acc = b1l[f];
        #pragma unroll
        for (int d = 0; d < DD; ++d) acc += h[d] * w1[f * DD + d];
        fv[f] = fmaxf(acc, 0.f);
      }
      #pragma unroll
      for (int od = 0; od < DD; ++od) {
        float acc = b2l[od];
        #pragma unroll
        for (int f = 0; f < FFD; ++f) acc += fv[f] * w2[od * FFD + f];
        h[od] += acc;
      }
      lnorm16(h, g2, be2);
    }
  }

  // ---- final LN (cls rows) + head ----
  __syncthreads();
  if (act && r == 0) {
    lnorm16(h, lnf_g, lnf_b);
    #pragma unroll
    for (int d = 0; d < DD; ++d) s_cls[j][d] = h[d];
  }
  __syncthreads();
  if (tid < NBATCH * NP) {
    const int jj = tid / NP;
    const int oo = tid - jj * NP;
    if (blockIdx.x * NBATCH + jj < B) {
      float acc = end_b[oo];
      #pragma unroll
      for (int d = 0; d < DD; ++d) acc += s_cls[jj][d] * end_w[oo * DD + d];
      s_lat[jj][oo] = acc * head_w[oo];
    }
  }
  __syncthreads();
  if (tid < NBATCH) {
    const int bb = blockIdx.x * NBATCH + tid;
    if (bb < B) {
      float acc = head_b[0];
      for (int o = 0; o < NP; ++o) acc += s_lat[tid][o];
      out[bb] = rcp_fast(1.f + exp2_fast(-acc * 1.4426950408889634f));
    }
  }
}

// ---------------- fallback kernel (R2 LDS version) if ws too small ----------------
#define FB_NBATCH 3
#define FB_NT 320
#define KROW 8
#define VROW 8
#define KREG (SS * KROW + 4)
#define VREG (SS * VROW + 2)
typedef float f2 __attribute__((ext_vector_type(2)));

__global__ __launch_bounds__(FB_NT)
void transformer_fwd_lds(const float* __restrict__ x,
                         const float* __restrict__ conv_w,  const float* __restrict__ conv_b,
                         const float* __restrict__ cls_emb,
                         const float* __restrict__ Wqkv,    const float* __restrict__ bqkv,
                         const float* __restrict__ Wo,      const float* __restrict__ bo,
                         const float* __restrict__ W1,      const float* __restrict__ b1,
                         const float* __restrict__ W2,      const float* __restrict__ b2,
                         const float* __restrict__ ln1_g,   const float* __restrict__ ln1_b,
                         const float* __restrict__ ln2_g,   const float* __restrict__ ln2_b,
                         const float* __restrict__ lnf_g,   const float* __restrict__ lnf_b,
                         const float* __restrict__ end_w,   const float* __restrict__ end_b,
                         const float* __restrict__ head_w,  const float* __restrict__ head_b,
                         float* __restrict__ out, int B)
{
  __shared__ h2    s_K[FB_NBATCH][KREG];
  __shared__ f2    s_V[FB_NBATCH][VREG];
  __shared__ float s_cls[FB_NBATCH][DD];
  __shared__ float s_lat[FB_NBATCH][NP];

  const int tid = threadIdx.x;
  const int j   = tid / SS;
  const int r   = tid - j * SS;
  const int b   = blockIdx.x * FB_NBATCH + j;
  const bool act = (tid < FB_NBATCH * SS) && (b < B);

  float h[DD];
  if (act) {
    if (r == 0) {
      #pragma unroll
      for (int d = 0; d < DD; ++d) h[d] = cls_emb[d];
    } else {
      const float* xp = x + (size_t)b * SEQ + (r - 1) * KK;
      float xv[KK];
      #pragma unroll
      for (int k = 0; k < KK; ++k) xv[k] = xp[k];
      #pragma unroll
      for (int f = 0; f < DD; ++f) {
        float acc = conv_b[f];
        #pragma unroll
        for (int k = 0; k < KK; ++k) acc += xv[k] * conv_w[f * KK + k];
        h[f] = acc;
      }
    }
  }

  const float qs = 1.4426950408889634f * 0.70710678118654752f;

  for (int l = 0; l < NL; ++l) {
    const float* wq  = Wqkv + l * (3 * DD * DD);
    const float* bq  = bqkv + l * (3 * DD);
    const float* wo  = Wo   + l * (DD * DD);
    const float* bol = bo   + l * DD;
    const float* w1  = W1   + l * (FFD * DD);
    const float* b1l = b1   + l * FFD;
    const float* w2  = W2   + l * (DD * FFD);
    const float* b2l = b2   + l * DD;
    const float* g1  = ln1_g + l * DD;  const float* be1 = ln1_b + l * DD;
    const float* g2  = ln2_g + l * DD;  const float* be2 = ln2_b + l * DD;

    __syncthreads();

    h2 q2[NH];
    if (act) {
      #pragma unroll
      for (int hh = 0; hh < NH; ++hh) {
        const int e0 = 2 * hh;
        float a0 = bq[e0], a1 = bq[e0 + 1];
        #pragma unroll
        for (int d = 0; d < DD; ++d) {
          a0 += h[d] * wq[e0 * DD + d];
          a1 += h[d] * wq[(e0 + 1) * DD + d];
        }
        q2[hh] = pk_h2(a0 * qs, a1 * qs);
      }
      h2* kw = &s_K[j][r * KROW];
      #pragma unroll
      for (int hh = 0; hh < NH; ++hh) {
        const int e0 = DD + 2 * hh;
        float a0 = bq[e0], a1 = bq[e0 + 1];
        #pragma unroll
        for (int d = 0; d < DD; ++d) {
          a0 += h[d] * wq[e0 * DD + d];
          a1 += h[d] * wq[(e0 + 1) * DD + d];
        }
        kw[hh] = pk_h2(a0, a1);
      }
      f2* vw = &s_V[j][r * VROW];
      #pragma unroll
      for (int hh = 0; hh < NH; ++hh) {
        const int e0 = 2 * DD + 2 * hh;
        float a0 = bq[e0], a1 = bq[e0 + 1];
        #pragma unroll
        for (int d = 0; d < DD; ++d) {
          a0 += h[d] * wq[e0 * DD + d];
          a1 += h[d] * wq[(e0 + 1) * DD + d];
        }
        f2 vv; vv.x = a0; vv.y = a1;
        vw[hh] = vv;
      }
    }
    __syncthreads();

    if (act) {
      float lsum[NH];
      f2 ctx[NH];
      #pragma unroll
      for (int hh = 0; hh < NH; ++hh) { lsum[hh] = 0.f; ctx[hh].x = 0.f; ctx[hh].y = 0.f; }
      const h2* kp0 = &s_K[j][0];
      const f2* vp0 = &s_V[j][0];
      for (int t = 0; t < SS; ++t) {
        const h2* kp = kp0 + t * KROW;
        const f2* vp = vp0 + t * VROW;
        #pragma unroll
        for (int hh = 0; hh < NH; ++hh) {
          const float p = exp2_fast(fdot2(q2[hh], kp[hh], 0.0f));
          lsum[hh] += p;
          ctx[hh]  += vp[hh] * p;
        }
      }
      float cx[DD];
      #pragma unroll
      for (int hh = 0; hh < NH; ++hh) {
        const float inv = rcp_fast(lsum[hh]);
        cx[2 * hh]     = ctx[hh].x * inv;
        cx[2 * hh + 1] = ctx[hh].y * inv;
      }
      #pragma unroll
      for (int od = 0; od < DD; ++od) {
        float acc = bol[od];
        #pragma unroll
        for (int d = 0; d < DD; ++d) acc += cx[d] * wo[od * DD + d];
        h[od] += acc;
      }
      lnorm16(h, g1, be1);
      float fv[FFD];
      #pragma unroll
      for (int f = 0; f < FFD; ++f) {
        float acc = b1l[f];
        #pragma unroll
        for (int d = 0; d < DD; ++d) acc += h[d] * w1[f * DD + d];
        fv[f] = fmaxf(acc, 0.f);
      }
      #pragma unroll
      for (int od = 0; od < DD; ++od) {
        float acc = b2l[od];
        #pragma unroll
        for (int f = 0; f < FFD; ++f) acc += fv[f] * w2[od * FFD + f];
        h[od] += acc;
      }
      lnorm16(h, g2, be2);
    }
  }

  __syncthreads();
  if (act && r == 0) {
    lnorm16(h, lnf_g, lnf_b);
    #pragma unroll
    for (int d = 0; d < DD; ++d) s_cls[j][d] = h[d];
  }
  __syncthreads();
  if (tid < FB_NBATCH * NP) {
    const int jj = tid / NP;
    const int oo = tid - jj * NP;
    if (blockIdx.x * FB_NBATCH + jj < B) {
      float acc = end_b[oo];
      #pragma unroll
      for (int d = 0; d < DD; ++d) acc += s_cls[jj][d] * end_w[oo * DD + d];
      s_lat[jj][oo] = acc * head_w[oo];
    }
  }
  __syncthreads();
  if (tid < FB_NBATCH) {
    const int bb = blockIdx.x * FB_NBATCH + tid;
    if (bb < B) {
      float acc = head_b[0];
      for (int o = 0; o < NP; ++o) acc += s_lat[tid][o];
      out[bb] = rcp_fast(1.f + exp2_fast(-acc * 1.4426950408889634f));
    }
  }
}

extern "C" void kernel_launch(void* const* d_in, const int* in_sizes, int n_in,
                              void* d_out, int out_size, void* d_ws, size_t ws_size,
                              hipStream_t stream) {
  const float* x       = (const float*)d_in[0];
  const float* conv_w  = (const float*)d_in[1];
  const float* conv_b  = (const float*)d_in[2];
  const float* cls_emb = (const float*)d_in[3];
  const float* Wqkv    = (const float*)d_in[4];
  const float* bqkv    = (const float*)d_in[5];
  const float* Wo      = (const float*)d_in[6];
  const float* bo      = (const float*)d_in[7];
  const float* W1      = (const float*)d_in[8];
  const float* b1      = (const float*)d_in[9];
  const float* W2      = (const float*)d_in[10];
  const float* b2      = (const float*)d_in[11];
  const float* ln1_g   = (const float*)d_in[12];
  const float* ln1_b   = (const float*)d_in[13];
  const float* ln2_g   = (const float*)d_in[14];
  const float* ln2_b   = (const float*)d_in[15];
  const float* lnf_g   = (const float*)d_in[16];
  const float* lnf_b   = (const float*)d_in[17];
  const float* end_w   = (const float*)d_in[18];
  const float* end_b   = (const float*)d_in[19];
  const float* head_w  = (const float*)d_in[20];
  const float* head_b  = (const float*)d_in[21];
  float* out = (float*)d_out;

  const int B = in_sizes[0] / SEQ;   // 2048

  if (ws_size >= (size_t)B * BATB) {
    const int nb = (B + NBATCH - 1) / NBATCH;   // 1024 -> exactly 4 blocks/CU
    transformer_fwd_g<<<nb, NT, 0, stream>>>(
        x, conv_w, conv_b, cls_emb, Wqkv, bqkv, Wo, bo, W1, b1, W2, b2,
        ln1_g, ln1_b, ln2_g, ln2_b, lnf_g, lnf_b, end_w, end_b, head_w, head_b,
        out, (char*)d_ws, B);
  } else {
    const int nb = (B + FB_NBATCH - 1) / FB_NBATCH;
    transformer_fwd_lds<<<nb, FB_NT, 0, stream>>>(
        x, conv_w, conv_b, cls_emb, Wqkv, bqkv, Wo, bo, W1, b1, W2, b2,
        ln1_g, ln1_b, ln2_g, ln2_b, lnf_g, lnf_b, end_w, end_b, head_w, head_b,
        out, B);
  }
}

// Round 4
// 590.139 us; speedup vs baseline: 1.3085x; 1.0702x over previous
//
#include <hip/hip_runtime.h>
#include <math.h>

// Problem constants
#define DD   16     // model dim
#define NH   8      // heads (head dim = 2)
#define NL   8      // layers
#define FFD  16     // ff dim
#define KK   35     // conv kernel / patch size
#define SEQ  3500   // input seq
#define NP   100    // patches
#define SS   101    // tokens (cls + patches)
#define NBATCH 2    // batches per block
#define NT   256    // 4 waves; grid = 1024 = 4 blocks/CU
#define ROWB 64     // bytes per kv row (32 B fp16 K + 32 B fp16 V)
#define BATB (SS * ROWB)          // 6464 B per batch kv region
#define NWPAIR 6144               // packed weight half2 count (24.6 KB)

typedef __fp16 h2 __attribute__((ext_vector_type(2)));

__device__ __forceinline__ float fdot2(h2 a, h2 b, float c) {
#if __has_builtin(__builtin_amdgcn_fdot2)
  return __builtin_amdgcn_fdot2(a, b, c, false);
#else
  return c + (float)a.x * (float)b.x + (float)a.y * (float)b.y;
#endif
}
__device__ __forceinline__ float exp2_fast(float x) {
#if __has_builtin(__builtin_amdgcn_exp2f)
  return __builtin_amdgcn_exp2f(x);
#else
  return exp2f(x);
#endif
}
__device__ __forceinline__ float rcp_fast(float x) {
#if __has_builtin(__builtin_amdgcn_rcpf)
  return __builtin_amdgcn_rcpf(x);
#else
  return 1.0f / x;
#endif
}
__device__ __forceinline__ h2 pk_h2(float a, float b) {
#if __has_builtin(__builtin_amdgcn_cvt_pkrtz)
  return __builtin_amdgcn_cvt_pkrtz(a, b);
#else
  h2 r; r.x = (__fp16)a; r.y = (__fp16)b; return r;
#endif
}
__device__ __forceinline__ unsigned pk_u(float a, float b) {
  return __builtin_bit_cast(unsigned, pk_h2(a, b));
}
__device__ __forceinline__ h2 as_h2(unsigned u) {
  return __builtin_bit_cast(h2, u);
}

__device__ __forceinline__ void lnorm16(float* h, const float* __restrict__ g,
                                        const float* __restrict__ bb) {
  float mu = 0.f;
  #pragma unroll
  for (int d = 0; d < DD; ++d) mu += h[d];
  mu *= (1.f / DD);
  float var = 0.f;
  #pragma unroll
  for (int d = 0; d < DD; ++d) { float c = h[d] - mu; var += c * c; }
  var *= (1.f / DD);
  const float r = rsqrtf(var + 1e-5f);
  #pragma unroll
  for (int d = 0; d < DD; ++d) h[d] = (h[d] - mu) * r * g[d] + bb[d];
}

// 16-dim dot via 8 x v_dot2_f32_f16 (weights pre-packed as half2)
__device__ __forceinline__ float dot16(const h2* hv, const unsigned* __restrict__ w, float acc) {
  #pragma unroll
  for (int i = 0; i < 8; ++i) acc = fdot2(hv[i], as_h2(w[i]), acc);
  return acc;
}

// ---- prep: pack [Wqkv|Wo|W1|W2] f32 pairs into half2 (layouts are row-major,
//      row length even -> consecutive pairs are exactly dot2 operands) ----
__global__ __launch_bounds__(256)
void pack_weights(const float* __restrict__ Wqkv, const float* __restrict__ Wo,
                  const float* __restrict__ W1,   const float* __restrict__ W2,
                  unsigned* __restrict__ dst)
{
  const int i = blockIdx.x * 256 + threadIdx.x;
  if (i >= NWPAIR) return;
  float a, b;
  if (i < 3072)      { a = Wqkv[2*i];        b = Wqkv[2*i+1]; }
  else if (i < 4096) { int j = i - 3072; a = Wo[2*j]; b = Wo[2*j+1]; }
  else if (i < 5120) { int j = i - 4096; a = W1[2*j]; b = W1[2*j+1]; }
  else               { int j = i - 5120; a = W2[2*j]; b = W2[2*j+1]; }
  dst[i] = pk_u(a, b);
}

// ---------------- primary kernel ----------------
__global__ __launch_bounds__(NT)
void transformer_fwd_g(const float* __restrict__ x,
                       const float* __restrict__ conv_w,  const float* __restrict__ conv_b,
                       const float* __restrict__ cls_emb,
                       const float* __restrict__ bqkv,
                       const float* __restrict__ bo,
                       const float* __restrict__ b1,
                       const float* __restrict__ b2,
                       const float* __restrict__ ln1_g,   const float* __restrict__ ln1_b,
                       const float* __restrict__ ln2_g,   const float* __restrict__ ln2_b,
                       const float* __restrict__ lnf_g,   const float* __restrict__ lnf_b,
                       const float* __restrict__ end_w,   const float* __restrict__ end_b,
                       const float* __restrict__ head_w,  const float* __restrict__ head_b,
                       float* __restrict__ out, char* __restrict__ ws,
                       const unsigned* __restrict__ wpk, int B)
{
  __shared__ float s_cls[NBATCH][DD];
  __shared__ float s_lat[NBATCH][NP];

  const int tid = threadIdx.x;
  const int j   = tid / SS;
  const int r   = tid - j * SS;
  const int b   = blockIdx.x * NBATCH + j;
  const bool act = (tid < NBATCH * SS) && (b < B);

  const uint4* kvreg = (const uint4*)(ws + (size_t)b * BATB);
  uint4*       kvwr  = (uint4*)(ws + (size_t)b * BATB);

  // ---- conv patch embed ----
  float h[DD];
  if (act) {
    if (r == 0) {
      #pragma unroll
      for (int d = 0; d < DD; ++d) h[d] = cls_emb[d];
    } else {
      const float* xp = x + (size_t)b * SEQ + (r - 1) * KK;
      float xv[KK];
      #pragma unroll
      for (int k = 0; k < KK; ++k) xv[k] = xp[k];
      #pragma unroll
      for (int f = 0; f < DD; ++f) {
        float acc = conv_b[f];
        #pragma unroll
        for (int k = 0; k < KK; ++k) acc += xv[k] * conv_w[f * KK + k];
        h[f] = acc;
      }
    }
  }

  const float qs = 1.4426950408889634f * 0.70710678118654752f; // log2e / sqrt(2)

  for (int l = 0; l < NL; ++l) {
    const unsigned* wq16 = wpk + l * 384;          // [48][8]
    const unsigned* wo16 = wpk + 3072 + l * 128;   // [16][8]
    const unsigned* w116 = wpk + 4096 + l * 128;   // [16][8]
    const unsigned* w216 = wpk + 5120 + l * 128;   // [16][8]
    const float* bq  = bqkv + l * (3 * DD);
    const float* bol = bo   + l * DD;
    const float* b1l = b1   + l * FFD;
    const float* b2l = b2   + l * DD;
    const float* g1  = ln1_g + l * DD;  const float* be1 = ln1_b + l * DD;
    const float* g2  = ln2_g + l * DD;  const float* be2 = ln2_b + l * DD;

    __syncthreads();   // prior t-loop reads of kv region complete

    h2 q2[NH];
    if (act) {
      // pack h into half2 pairs once
      h2 hv[8];
      #pragma unroll
      for (int i = 0; i < 8; ++i) hv[i] = pk_h2(h[2*i], h[2*i+1]);

      // q (pre-scaled fp16 pairs)
      #pragma unroll
      for (int hh = 0; hh < NH; ++hh) {
        const float a0 = dot16(hv, &wq16[(2*hh    ) * 8], bq[2*hh]);
        const float a1 = dot16(hv, &wq16[(2*hh + 1) * 8], bq[2*hh+1]);
        q2[hh] = pk_h2(a0 * qs, a1 * qs);
      }
      // k, v -> fp16 packed row (64 B)
      unsigned row[16];
      #pragma unroll
      for (int e = 0; e < 16; e += 2) {  // k: e0 = 16..31
        const float a0 = dot16(hv, &wq16[(DD + e    ) * 8], bq[DD + e]);
        const float a1 = dot16(hv, &wq16[(DD + e + 1) * 8], bq[DD + e + 1]);
        row[e >> 1] = pk_u(a0, a1);
      }
      #pragma unroll
      for (int e = 0; e < 16; e += 2) {  // v: e0 = 32..47
        const float a0 = dot16(hv, &wq16[(2*DD + e    ) * 8], bq[2*DD + e]);
        const float a1 = dot16(hv, &wq16[(2*DD + e + 1) * 8], bq[2*DD + e + 1]);
        row[8 + (e >> 1)] = pk_u(a0, a1);
      }
      uint4* dst = kvwr + (size_t)r * 4;
      dst[0] = make_uint4(row[0],  row[1],  row[2],  row[3]);
      dst[1] = make_uint4(row[4],  row[5],  row[6],  row[7]);
      dst[2] = make_uint4(row[8],  row[9],  row[10], row[11]);
      dst[3] = make_uint4(row[12], row[13], row[14], row[15]);
    }
    __syncthreads();   // kv visible block-wide

    if (act) {
      // ---- attention: prefetch-pipelined wave-uniform kv loads ----
      float lsum[NH], cxx[NH], cxy[NH];
      #pragma unroll
      for (int hh = 0; hh < NH; ++hh) { lsum[hh] = 0.f; cxx[hh] = 0.f; cxy[hh] = 0.f; }

      uint4 c0 = kvreg[0], c1 = kvreg[1], c2 = kvreg[2], c3 = kvreg[3];
      #pragma unroll 2
      for (int t = 0; t < SS; ++t) {
        const int tn = (t + 1 < SS) ? (t + 1) : t;
        const uint4* np = kvreg + 4 * tn;
        const uint4 n0 = np[0], n1 = np[1], n2 = np[2], n3 = np[3];

        const unsigned ku[8] = {c0.x, c0.y, c0.z, c0.w, c1.x, c1.y, c1.z, c1.w};
        const unsigned vu[8] = {c2.x, c2.y, c2.z, c2.w, c3.x, c3.y, c3.z, c3.w};
        #pragma unroll
        for (int hh = 0; hh < NH; ++hh) {
          const h2 kk = as_h2(ku[hh]);
          const h2 vv = as_h2(vu[hh]);
          const float p = exp2_fast(fdot2(q2[hh], kk, 0.0f));
          lsum[hh] += p;
          cxx[hh]  += (float)vv.x * p;   // v_fma_mix
          cxy[hh]  += (float)vv.y * p;
        }
        c0 = n0; c1 = n1; c2 = n2; c3 = n3;
      }

      float cx[DD];
      #pragma unroll
      for (int hh = 0; hh < NH; ++hh) {
        const float inv = rcp_fast(lsum[hh]);
        cx[2 * hh]     = cxx[hh] * inv;
        cx[2 * hh + 1] = cxy[hh] * inv;
      }

      // ---- Wo + residual + LN1 (dot2 weights) ----
      h2 cv[8];
      #pragma unroll
      for (int i = 0; i < 8; ++i) cv[i] = pk_h2(cx[2*i], cx[2*i+1]);
      #pragma unroll
      for (int od = 0; od < DD; ++od)
        h[od] += dot16(cv, &wo16[od * 8], bol[od]);
      lnorm16(h, g1, be1);

      // ---- FF + residual + LN2 (dot2 weights) ----
      h2 hv2[8];
      #pragma unroll
      for (int i = 0; i < 8; ++i) hv2[i] = pk_h2(h[2*i], h[2*i+1]);
      float fv[FFD];
      #pragma unroll
      for (int f = 0; f < FFD; ++f)
        fv[f] = fmaxf(dot16(hv2, &w116[f * 8], b1l[f]), 0.f);
      h2 fv2[8];
      #pragma unroll
      for (int i = 0; i < 8; ++i) fv2[i] = pk_h2(fv[2*i], fv[2*i+1]);
      #pragma unroll
      for (int od = 0; od < DD; ++od)
        h[od] += dot16(fv2, &w216[od * 8], b2l[od]);
      lnorm16(h, g2, be2);
    }
  }

  // ---- final LN (cls rows) + head ----
  __syncthreads();
  if (act && r == 0) {
    lnorm16(h, lnf_g, lnf_b);
    #pragma unroll
    for (int d = 0; d < DD; ++d) s_cls[j][d] = h[d];
  }
  __syncthreads();
  if (tid < NBATCH * NP) {
    const int jj = tid / NP;
    const int oo = tid - jj * NP;
    if (blockIdx.x * NBATCH + jj < B) {
      float acc = end_b[oo];
      #pragma unroll
      for (int d = 0; d < DD; ++d) acc += s_cls[jj][d] * end_w[oo * DD + d];
      s_lat[jj][oo] = acc * head_w[oo];
    }
  }
  __syncthreads();
  if (tid < NBATCH) {
    const int bb = blockIdx.x * NBATCH + tid;
    if (bb < B) {
      float acc = head_b[0];
      for (int o = 0; o < NP; ++o) acc += s_lat[tid][o];
      out[bb] = rcp_fast(1.f + exp2_fast(-acc * 1.4426950408889634f));
    }
  }
}

// ---------------- fallback (LDS kv, f32 weights) if ws too small --------------
#define FB_NBATCH 3
#define FB_NT 320
#define KROW 8
#define VROW 8
#define KREG (SS * KROW + 4)
#define VREG (SS * VROW + 2)
typedef float f2 __attribute__((ext_vector_type(2)));

__global__ __launch_bounds__(FB_NT)
void transformer_fwd_lds(const float* __restrict__ x,
                         const float* __restrict__ conv_w,  const float* __restrict__ conv_b,
                         const float* __restrict__ cls_emb,
                         const float* __restrict__ Wqkv,    const float* __restrict__ bqkv,
                         const float* __restrict__ Wo,      const float* __restrict__ bo,
                         const float* __restrict__ W1,      const float* __restrict__ b1,
                         const float* __restrict__ W2,      const float* __restrict__ b2,
                         const float* __restrict__ ln1_g,   const float* __restrict__ ln1_b,
                         const float* __restrict__ ln2_g,   const float* __restrict__ ln2_b,
                         const float* __restrict__ lnf_g,   const float* __restrict__ lnf_b,
                         const float* __restrict__ end_w,   const float* __restrict__ end_b,
                         const float* __restrict__ head_w,  const float* __restrict__ head_b,
                         float* __restrict__ out, int B)
{
  __shared__ h2    s_K[FB_NBATCH][KREG];
  __shared__ f2    s_V[FB_NBATCH][VREG];
  __shared__ float s_cls[FB_NBATCH][DD];
  __shared__ float s_lat[FB_NBATCH][NP];

  const int tid = threadIdx.x;
  const int j   = tid / SS;
  const int r   = tid - j * SS;
  const int b   = blockIdx.x * FB_NBATCH + j;
  const bool act = (tid < FB_NBATCH * SS) && (b < B);

  float h[DD];
  if (act) {
    if (r == 0) {
      #pragma unroll
      for (int d = 0; d < DD; ++d) h[d] = cls_emb[d];
    } else {
      const float* xp = x + (size_t)b * SEQ + (r - 1) * KK;
      float xv[KK];
      #pragma unroll
      for (int k = 0; k < KK; ++k) xv[k] = xp[k];
      #pragma unroll
      for (int f = 0; f < DD; ++f) {
        float acc = conv_b[f];
        #pragma unroll
        for (int k = 0; k < KK; ++k) acc += xv[k] * conv_w[f * KK + k];
        h[f] = acc;
      }
    }
  }

  const float qs = 1.4426950408889634f * 0.70710678118654752f;

  for (int l = 0; l < NL; ++l) {
    const float* wq  = Wqkv + l * (3 * DD * DD);
    const float* bq  = bqkv + l * (3 * DD);
    const float* wo  = Wo   + l * (DD * DD);
    const float* bol = bo   + l * DD;
    const float* w1  = W1   + l * (FFD * DD);
    const float* b1l = b1   + l * FFD;
    const float* w2  = W2   + l * (DD * FFD);
    const float* b2l = b2   + l * DD;
    const float* g1  = ln1_g + l * DD;  const float* be1 = ln1_b + l * DD;
    const float* g2  = ln2_g + l * DD;  const float* be2 = ln2_b + l * DD;

    __syncthreads();

    h2 q2[NH];
    if (act) {
      #pragma unroll
      for (int hh = 0; hh < NH; ++hh) {
        const int e0 = 2 * hh;
        float a0 = bq[e0], a1 = bq[e0 + 1];
        #pragma unroll
        for (int d = 0; d < DD; ++d) {
          a0 += h[d] * wq[e0 * DD + d];
          a1 += h[d] * wq[(e0 + 1) * DD + d];
        }
        q2[hh] = pk_h2(a0 * qs, a1 * qs);
      }
      h2* kw = &s_K[j][r * KROW];
      #pragma unroll
      for (int hh = 0; hh < NH; ++hh) {
        const int e0 = DD + 2 * hh;
        float a0 = bq[e0], a1 = bq[e0 + 1];
        #pragma unroll
        for (int d = 0; d < DD; ++d) {
          a0 += h[d] * wq[e0 * DD + d];
          a1 += h[d] * wq[(e0 + 1) * DD + d];
        }
        kw[hh] = pk_h2(a0, a1);
      }
      f2* vw = &s_V[j][r * VROW];
      #pragma unroll
      for (int hh = 0; hh < NH; ++hh) {
        const int e0 = 2 * DD + 2 * hh;
        float a0 = bq[e0], a1 = bq[e0 + 1];
        #pragma unroll
        for (int d = 0; d < DD; ++d) {
          a0 += h[d] * wq[e0 * DD + d];
          a1 += h[d] * wq[(e0 + 1) * DD + d];
        }
        f2 vv; vv.x = a0; vv.y = a1;
        vw[hh] = vv;
      }
    }
    __syncthreads();

    if (act) {
      float lsum[NH];
      f2 ctx[NH];
      #pragma unroll
      for (int hh = 0; hh < NH; ++hh) { lsum[hh] = 0.f; ctx[hh].x = 0.f; ctx[hh].y = 0.f; }
      const h2* kp0 = &s_K[j][0];
      const f2* vp0 = &s_V[j][0];
      for (int t = 0; t < SS; ++t) {
        const h2* kp = kp0 + t * KROW;
        const f2* vp = vp0 + t * VROW;
        #pragma unroll
        for (int hh = 0; hh < NH; ++hh) {
          const float p = exp2_fast(fdot2(q2[hh], kp[hh], 0.0f));
          lsum[hh] += p;
          ctx[hh]  += vp[hh] * p;
        }
      }
      float cx[DD];
      #pragma unroll
      for (int hh = 0; hh < NH; ++hh) {
        const float inv = rcp_fast(lsum[hh]);
        cx[2 * hh]     = ctx[hh].x * inv;
        cx[2 * hh + 1] = ctx[hh].y * inv;
      }
      #pragma unroll
      for (int od = 0; od < DD; ++od) {
        float acc = bol[od];
        #pragma unroll
        for (int d = 0; d < DD; ++d) acc += cx[d] * wo[od * DD + d];
        h[od] += acc;
      }
      lnorm16(h, g1, be1);
      float fv[FFD];
      #pragma unroll
      for (int f = 0; f < FFD; ++f) {
        float acc = b1l[f];
        #pragma unroll
        for (int d = 0; d < DD; ++d) acc += h[d] * w1[f * DD + d];
        fv[f] = fmaxf(acc, 0.f);
      }
      #pragma unroll
      for (int od = 0; od < DD; ++od) {
        float acc = b2l[od];
        #pragma unroll
        for (int f = 0; f < FFD; ++f) acc += fv[f] * w2[od * FFD + f];
        h[od] += acc;
      }
      lnorm16(h, g2, be2);
    }
  }

  __syncthreads();
  if (act && r == 0) {
    lnorm16(h, lnf_g, lnf_b);
    #pragma unroll
    for (int d = 0; d < DD; ++d) s_cls[j][d] = h[d];
  }
  __syncthreads();
  if (tid < FB_NBATCH * NP) {
    const int jj = tid / NP;
    const int oo = tid - jj * NP;
    if (blockIdx.x * FB_NBATCH + jj < B) {
      float acc = end_b[oo];
      #pragma unroll
      for (int d = 0; d < DD; ++d) acc += s_cls[jj][d] * end_w[oo * DD + d];
      s_lat[jj][oo] = acc * head_w[oo];
    }
  }
  __syncthreads();
  if (tid < FB_NBATCH) {
    const int bb = blockIdx.x * FB_NBATCH + tid;
    if (bb < B) {
      float acc = head_b[0];
      for (int o = 0; o < NP; ++o) acc += s_lat[tid][o];
      out[bb] = rcp_fast(1.f + exp2_fast(-acc * 1.4426950408889634f));
    }
  }
}

extern "C" void kernel_launch(void* const* d_in, const int* in_sizes, int n_in,
                              void* d_out, int out_size, void* d_ws, size_t ws_size,
                              hipStream_t stream) {
  const float* x       = (const float*)d_in[0];
  const float* conv_w  = (const float*)d_in[1];
  const float* conv_b  = (const float*)d_in[2];
  const float* cls_emb = (const float*)d_in[3];
  const float* Wqkv    = (const float*)d_in[4];
  const float* bqkv    = (const float*)d_in[5];
  const float* Wo      = (const float*)d_in[6];
  const float* bo      = (const float*)d_in[7];
  const float* W1      = (const float*)d_in[8];
  const float* b1      = (const float*)d_in[9];
  const float* W2      = (const float*)d_in[10];
  const float* b2      = (const float*)d_in[11];
  const float* ln1_g   = (const float*)d_in[12];
  const float* ln1_b   = (const float*)d_in[13];
  const float* ln2_g   = (const float*)d_in[14];
  const float* ln2_b   = (const float*)d_in[15];
  const float* lnf_g   = (const float*)d_in[16];
  const float* lnf_b   = (const float*)d_in[17];
  const float* end_w   = (const float*)d_in[18];
  const float* end_b   = (const float*)d_in[19];
  const float* head_w  = (const float*)d_in[20];
  const float* head_b  = (const float*)d_in[21];
  float* out = (float*)d_out;

  const int B = in_sizes[0] / SEQ;   // 2048
  const size_t kv_bytes = (size_t)B * BATB;
  const size_t need     = kv_bytes + NWPAIR * sizeof(unsigned);

  if (ws_size >= need) {
    unsigned* wpk = (unsigned*)((char*)d_ws + kv_bytes);
    pack_weights<<<(NWPAIR + 255) / 256, 256, 0, stream>>>(Wqkv, Wo, W1, W2, wpk);
    const int nb = (B + NBATCH - 1) / NBATCH;   // 1024
    transformer_fwd_g<<<nb, NT, 0, stream>>>(
        x, conv_w, conv_b, cls_emb, bqkv, bo, b1, b2,
        ln1_g, ln1_b, ln2_g, ln2_b, lnf_g, lnf_b, end_w, end_b, head_w, head_b,
        out, (char*)d_ws, wpk, B);
  } else {
    const int nb = (B + FB_NBATCH - 1) / FB_NBATCH;
    transformer_fwd_lds<<<nb, FB_NT, 0, stream>>>(
        x, conv_w, conv_b, cls_emb, Wqkv, bqkv, Wo, bo, W1, b1, W2, b2,
        ln1_g, ln1_b, ln2_g, ln2_b, lnf_g, lnf_b, end_w, end_b, head_w, head_b,
        out, B);
  }
}

// Round 5
// 590.111 us; speedup vs baseline: 1.3086x; 1.0000x over previous
//
#include <hip/hip_runtime.h>
#include <math.h>

// Problem constants
#define DD   16     // model dim
#define NH   8      // heads (head dim = 2)
#define NL   8      // layers
#define FFD  16     // ff dim
#define KK   35     // conv kernel / patch size
#define SEQ  3500   // input seq
#define NP   100    // patches
#define SS   101    // tokens (cls + patches)
#define NBATCH 2    // batches per block; batch slot = wave>>1 (wave-uniform!)
#define NT   256    // 4 waves; grid = 1024 = 4 blocks/CU, 16 waves/CU
#define ROWDW 20    // dwords per kv row in LDS (80 B: K 8 dw + V 8 dw + 4 pad)
#define NROW 102    // 101 rows + 1 pad row (unconditional prefetch of t+1)
#define NWPAIR 6144 // packed weight half2 count (24.6 KB in d_ws)

typedef __fp16 h2 __attribute__((ext_vector_type(2)));

__device__ __forceinline__ float fdot2(h2 a, h2 b, float c) {
#if __has_builtin(__builtin_amdgcn_fdot2)
  return __builtin_amdgcn_fdot2(a, b, c, false);
#else
  return c + (float)a.x * (float)b.x + (float)a.y * (float)b.y;
#endif
}
__device__ __forceinline__ float exp2_fast(float x) {
#if __has_builtin(__builtin_amdgcn_exp2f)
  return __builtin_amdgcn_exp2f(x);
#else
  return exp2f(x);
#endif
}
__device__ __forceinline__ float rcp_fast(float x) {
#if __has_builtin(__builtin_amdgcn_rcpf)
  return __builtin_amdgcn_rcpf(x);
#else
  return 1.0f / x;
#endif
}
__device__ __forceinline__ h2 pk_h2(float a, float b) {
#if __has_builtin(__builtin_amdgcn_cvt_pkrtz)
  return __builtin_amdgcn_cvt_pkrtz(a, b);
#else
  h2 r; r.x = (__fp16)a; r.y = (__fp16)b; return r;
#endif
}
__device__ __forceinline__ unsigned pk_u(float a, float b) {
  return __builtin_bit_cast(unsigned, pk_h2(a, b));
}
__device__ __forceinline__ h2 as_h2(unsigned u) {
  return __builtin_bit_cast(h2, u);
}

__device__ __forceinline__ void lnorm16(float* h, const float* __restrict__ g,
                                        const float* __restrict__ bb) {
  float mu = 0.f;
  #pragma unroll
  for (int d = 0; d < DD; ++d) mu += h[d];
  mu *= (1.f / DD);
  float var = 0.f;
  #pragma unroll
  for (int d = 0; d < DD; ++d) { float c = h[d] - mu; var += c * c; }
  var *= (1.f / DD);
  const float r = rsqrtf(var + 1e-5f);
  #pragma unroll
  for (int d = 0; d < DD; ++d) h[d] = (h[d] - mu) * r * g[d] + bb[d];
}

// 16-dim dot via 8 x v_dot2_f32_f16 (weights pre-packed as half2)
__device__ __forceinline__ float dot16(const h2* hv, const unsigned* __restrict__ w, float acc) {
  #pragma unroll
  for (int i = 0; i < 8; ++i) acc = fdot2(hv[i], as_h2(w[i]), acc);
  return acc;
}

// ---- prep: pack [Wqkv|Wo|W1|W2] f32 pairs into half2 ----
__global__ __launch_bounds__(256)
void pack_weights(const float* __restrict__ Wqkv, const float* __restrict__ Wo,
                  const float* __restrict__ W1,   const float* __restrict__ W2,
                  unsigned* __restrict__ dst)
{
  const int i = blockIdx.x * 256 + threadIdx.x;
  if (i >= NWPAIR) return;
  float a, b;
  if (i < 3072)      { a = Wqkv[2*i];        b = Wqkv[2*i+1]; }
  else if (i < 4096) { int j = i - 3072; a = Wo[2*j]; b = Wo[2*j+1]; }
  else if (i < 5120) { int j = i - 4096; a = W1[2*j]; b = W1[2*j+1]; }
  else               { int j = i - 5120; a = W2[2*j]; b = W2[2*j+1]; }
  dst[i] = pk_u(a, b);
}

// ---------------- primary kernel: wave-uniform batch, kv in LDS ----------------
__global__ __launch_bounds__(NT, 4)
void transformer_fwd_g(const float* __restrict__ x,
                       const float* __restrict__ conv_w,  const float* __restrict__ conv_b,
                       const float* __restrict__ cls_emb,
                       const float* __restrict__ bqkv,
                       const float* __restrict__ bo,
                       const float* __restrict__ b1,
                       const float* __restrict__ b2,
                       const float* __restrict__ ln1_g,   const float* __restrict__ ln1_b,
                       const float* __restrict__ ln2_g,   const float* __restrict__ ln2_b,
                       const float* __restrict__ lnf_g,   const float* __restrict__ lnf_b,
                       const float* __restrict__ end_w,   const float* __restrict__ end_b,
                       const float* __restrict__ head_w,  const float* __restrict__ head_b,
                       float* __restrict__ out,
                       const unsigned* __restrict__ wpk, int B)
{
  // kv row: 80 B (K 8 dw | V 8 dw | 4 dw pad) -> scatter writes spread banks;
  // t-loop reads are wave-uniform => LDS broadcast, conflict-free.
  __shared__ unsigned s_kv[NBATCH][NROW * ROWDW];
  __shared__ float s_cls[NBATCH][DD];
  __shared__ float s_lat[NBATCH][NP];

  const int tid  = threadIdx.x;
  const int wid  = tid >> 6;               // wave 0..3
  const int lane = tid & 63;
  const int j    = wid >> 1;               // batch slot: waves {0,1}->0, {2,3}->1 (wave-uniform)
  const int r    = ((wid & 1) << 6) + lane; // row 0..127
  const int b    = blockIdx.x * NBATCH + j;
  const bool act = (r < SS) && (b < B);

  // ---- conv patch embed ----
  float h[DD];
  if (act) {
    if (r == 0) {
      #pragma unroll
      for (int d = 0; d < DD; ++d) h[d] = cls_emb[d];
    } else {
      const float* xp = x + (size_t)b * SEQ + (r - 1) * KK;
      float xv[KK];
      #pragma unroll
      for (int k = 0; k < KK; ++k) xv[k] = xp[k];
      #pragma unroll
      for (int f = 0; f < DD; ++f) {
        float acc = conv_b[f];
        #pragma unroll
        for (int k = 0; k < KK; ++k) acc += xv[k] * conv_w[f * KK + k];
        h[f] = acc;
      }
    }
  }

  const float qs = 1.4426950408889634f * 0.70710678118654752f; // log2e / sqrt(2)

  for (int l = 0; l < NL; ++l) {
    const unsigned* wq16 = wpk + l * 384;          // [48][8]
    const unsigned* wo16 = wpk + 3072 + l * 128;   // [16][8]
    const unsigned* w116 = wpk + 4096 + l * 128;   // [16][8]
    const unsigned* w216 = wpk + 5120 + l * 128;   // [16][8]
    const float* bq  = bqkv + l * (3 * DD);
    const float* bol = bo   + l * DD;
    const float* b1l = b1   + l * FFD;
    const float* b2l = b2   + l * DD;
    const float* g1  = ln1_g + l * DD;  const float* be1 = ln1_b + l * DD;
    const float* g2  = ln2_g + l * DD;  const float* be2 = ln2_b + l * DD;

    __syncthreads();   // prior t-loop reads of s_kv complete

    h2 q2[NH];
    if (act) {
      // pack h into half2 pairs once
      h2 hv[8];
      #pragma unroll
      for (int i = 0; i < 8; ++i) hv[i] = pk_h2(h[2*i], h[2*i+1]);

      // q (pre-scaled fp16 pairs)
      #pragma unroll
      for (int hh = 0; hh < NH; ++hh) {
        const float a0 = dot16(hv, &wq16[(2*hh    ) * 8], bq[2*hh]);
        const float a1 = dot16(hv, &wq16[(2*hh + 1) * 8], bq[2*hh+1]);
        q2[hh] = pk_h2(a0 * qs, a1 * qs);
      }
      // k, v -> fp16 packed row (64 B) in LDS
      unsigned row[16];
      #pragma unroll
      for (int e = 0; e < 16; e += 2) {  // k
        const float a0 = dot16(hv, &wq16[(DD + e    ) * 8], bq[DD + e]);
        const float a1 = dot16(hv, &wq16[(DD + e + 1) * 8], bq[DD + e + 1]);
        row[e >> 1] = pk_u(a0, a1);
      }
      #pragma unroll
      for (int e = 0; e < 16; e += 2) {  // v
        const float a0 = dot16(hv, &wq16[(2*DD + e    ) * 8], bq[2*DD + e]);
        const float a1 = dot16(hv, &wq16[(2*DD + e + 1) * 8], bq[2*DD + e + 1]);
        row[8 + (e >> 1)] = pk_u(a0, a1);
      }
      uint4* dst = (uint4*)&s_kv[j][r * ROWDW];
      dst[0] = make_uint4(row[0],  row[1],  row[2],  row[3]);
      dst[1] = make_uint4(row[4],  row[5],  row[6],  row[7]);
      dst[2] = make_uint4(row[8],  row[9],  row[10], row[11]);
      dst[3] = make_uint4(row[12], row[13], row[14], row[15]);
    }
    __syncthreads();   // kv visible block-wide

    if (act) {
      // ---- attention: wave-uniform LDS broadcast reads, prefetch depth 1 ----
      float lsum[NH], cxx[NH], cxy[NH];
      #pragma unroll
      for (int hh = 0; hh < NH; ++hh) { lsum[hh] = 0.f; cxx[hh] = 0.f; cxy[hh] = 0.f; }

      const uint4* kv = (const uint4*)&s_kv[j][0];  // row t at uint4 offset 5*t
      uint4 c0 = kv[0], c1 = kv[1], c2 = kv[2], c3 = kv[3];
      #pragma unroll 2
      for (int t = 0; t < SS; ++t) {
        const uint4* np = kv + 5 * (t + 1);         // pad row makes t=100 safe
        const uint4 n0 = np[0], n1 = np[1], n2 = np[2], n3 = np[3];

        const unsigned ku[8] = {c0.x, c0.y, c0.z, c0.w, c1.x, c1.y, c1.z, c1.w};
        const unsigned vu[8] = {c2.x, c2.y, c2.z, c2.w, c3.x, c3.y, c3.z, c3.w};
        #pragma unroll
        for (int hh = 0; hh < NH; ++hh) {
          const h2 kk = as_h2(ku[hh]);
          const h2 vv = as_h2(vu[hh]);
          const float p = exp2_fast(fdot2(q2[hh], kk, 0.0f));
          lsum[hh] += p;
          cxx[hh]  += (float)vv.x * p;   // v_fma_mix
          cxy[hh]  += (float)vv.y * p;
        }
        c0 = n0; c1 = n1; c2 = n2; c3 = n3;
      }

      float cx[DD];
      #pragma unroll
      for (int hh = 0; hh < NH; ++hh) {
        const float inv = rcp_fast(lsum[hh]);
        cx[2 * hh]     = cxx[hh] * inv;
        cx[2 * hh + 1] = cxy[hh] * inv;
      }

      // ---- Wo + residual + LN1 (dot2 weights) ----
      h2 cv[8];
      #pragma unroll
      for (int i = 0; i < 8; ++i) cv[i] = pk_h2(cx[2*i], cx[2*i+1]);
      #pragma unroll
      for (int od = 0; od < DD; ++od)
        h[od] += dot16(cv, &wo16[od * 8], bol[od]);
      lnorm16(h, g1, be1);

      // ---- FF + residual + LN2 (dot2 weights) ----
      h2 hv2[8];
      #pragma unroll
      for (int i = 0; i < 8; ++i) hv2[i] = pk_h2(h[2*i], h[2*i+1]);
      float fv[FFD];
      #pragma unroll
      for (int f = 0; f < FFD; ++f)
        fv[f] = fmaxf(dot16(hv2, &w116[f * 8], b1l[f]), 0.f);
      h2 fv2[8];
      #pragma unroll
      for (int i = 0; i < 8; ++i) fv2[i] = pk_h2(fv[2*i], fv[2*i+1]);
      #pragma unroll
      for (int od = 0; od < DD; ++od)
        h[od] += dot16(fv2, &w216[od * 8], b2l[od]);
      lnorm16(h, g2, be2);
    }
  }

  // ---- final LN (cls rows) + head ----
  __syncthreads();
  if (act && r == 0) {
    lnorm16(h, lnf_g, lnf_b);
    #pragma unroll
    for (int d = 0; d < DD; ++d) s_cls[j][d] = h[d];
  }
  __syncthreads();
  if (tid < NBATCH * NP) {
    const int jj = tid / NP;
    const int oo = tid - jj * NP;
    if (blockIdx.x * NBATCH + jj < B) {
      float acc = end_b[oo];
      #pragma unroll
      for (int d = 0; d < DD; ++d) acc += s_cls[jj][d] * end_w[oo * DD + d];
      s_lat[jj][oo] = acc * head_w[oo];
    }
  }
  __syncthreads();
  if (tid < NBATCH) {
    const int bb = blockIdx.x * NBATCH + tid;
    if (bb < B) {
      float acc = head_b[0];
      for (int o = 0; o < NP; ++o) acc += s_lat[tid][o];
      out[bb] = rcp_fast(1.f + exp2_fast(-acc * 1.4426950408889634f));
    }
  }
}

// ---------------- fallback (no ws needed): f32 weights, LDS kv ----------------
#define FB_NBATCH 3
#define FB_NT 320
#define KROW 8
#define VROW 8
#define KREG (SS * KROW + 4)
#define VREG (SS * VROW + 2)
typedef float f2 __attribute__((ext_vector_type(2)));

__global__ __launch_bounds__(FB_NT)
void transformer_fwd_lds(const float* __restrict__ x,
                         const float* __restrict__ conv_w,  const float* __restrict__ conv_b,
                         const float* __restrict__ cls_emb,
                         const float* __restrict__ Wqkv,    const float* __restrict__ bqkv,
                         const float* __restrict__ Wo,      const float* __restrict__ bo,
                         const float* __restrict__ W1,      const float* __restrict__ b1,
                         const float* __restrict__ W2,      const float* __restrict__ b2,
                         const float* __restrict__ ln1_g,   const float* __restrict__ ln1_b,
                         const float* __restrict__ ln2_g,   const float* __restrict__ ln2_b,
                         const float* __restrict__ lnf_g,   const float* __restrict__ lnf_b,
                         const float* __restrict__ end_w,   const float* __restrict__ end_b,
                         const float* __restrict__ head_w,  const float* __restrict__ head_b,
                         float* __restrict__ out, int B)
{
  __shared__ h2    s_K[FB_NBATCH][KREG];
  __shared__ f2    s_V[FB_NBATCH][VREG];
  __shared__ float s_cls[FB_NBATCH][DD];
  __shared__ float s_lat[FB_NBATCH][NP];

  const int tid = threadIdx.x;
  const int j   = tid / SS;
  const int r   = tid - j * SS;
  const int b   = blockIdx.x * FB_NBATCH + j;
  const bool act = (tid < FB_NBATCH * SS) && (b < B);

  float h[DD];
  if (act) {
    if (r == 0) {
      #pragma unroll
      for (int d = 0; d < DD; ++d) h[d] = cls_emb[d];
    } else {
      const float* xp = x + (size_t)b * SEQ + (r - 1) * KK;
      float xv[KK];
      #pragma unroll
      for (int k = 0; k < KK; ++k) xv[k] = xp[k];
      #pragma unroll
      for (int f = 0; f < DD; ++f) {
        float acc = conv_b[f];
        #pragma unroll
        for (int k = 0; k < KK; ++k) acc += xv[k] * conv_w[f * KK + k];
        h[f] = acc;
      }
    }
  }

  const float qs = 1.4426950408889634f * 0.70710678118654752f;

  for (int l = 0; l < NL; ++l) {
    const float* wq  = Wqkv + l * (3 * DD * DD);
    const float* bq  = bqkv + l * (3 * DD);
    const float* wo  = Wo   + l * (DD * DD);
    const float* bol = bo   + l * DD;
    const float* w1  = W1   + l * (FFD * DD);
    const float* b1l = b1   + l * FFD;
    const float* w2  = W2   + l * (DD * FFD);
    const float* b2l = b2   + l * DD;
    const float* g1  = ln1_g + l * DD;  const float* be1 = ln1_b + l * DD;
    const float* g2  = ln2_g + l * DD;  const float* be2 = ln2_b + l * DD;

    __syncthreads();

    h2 q2[NH];
    if (act) {
      #pragma unroll
      for (int hh = 0; hh < NH; ++hh) {
        const int e0 = 2 * hh;
        float a0 = bq[e0], a1 = bq[e0 + 1];
        #pragma unroll
        for (int d = 0; d < DD; ++d) {
          a0 += h[d] * wq[e0 * DD + d];
          a1 += h[d] * wq[(e0 + 1) * DD + d];
        }
        q2[hh] = pk_h2(a0 * qs, a1 * qs);
      }
      h2* kw = &s_K[j][r * KROW];
      #pragma unroll
      for (int hh = 0; hh < NH; ++hh) {
        const int e0 = DD + 2 * hh;
        float a0 = bq[e0], a1 = bq[e0 + 1];
        #pragma unroll
        for (int d = 0; d < DD; ++d) {
          a0 += h[d] * wq[e0 * DD + d];
          a1 += h[d] * wq[(e0 + 1) * DD + d];
        }
        kw[hh] = pk_h2(a0, a1);
      }
      f2* vw = &s_V[j][r * VROW];
      #pragma unroll
      for (int hh = 0; hh < NH; ++hh) {
        const int e0 = 2 * DD + 2 * hh;
        float a0 = bq[e0], a1 = bq[e0 + 1];
        #pragma unroll
        for (int d = 0; d < DD; ++d) {
          a0 += h[d] * wq[e0 * DD + d];
          a1 += h[d] * wq[(e0 + 1) * DD + d];
        }
        f2 vv; vv.x = a0; vv.y = a1;
        vw[hh] = vv;
      }
    }
    __syncthreads();

    if (act) {
      float lsum[NH];
      f2 ctx[NH];
      #pragma unroll
      for (int hh = 0; hh < NH; ++hh) { lsum[hh] = 0.f; ctx[hh].x = 0.f; ctx[hh].y = 0.f; }
      const h2* kp0 = &s_K[j][0];
      const f2* vp0 = &s_V[j][0];
      for (int t = 0; t < SS; ++t) {
        const h2* kp = kp0 + t * KROW;
        const f2* vp = vp0 + t * VROW;
        #pragma unroll
        for (int hh = 0; hh < NH; ++hh) {
          const float p = exp2_fast(fdot2(q2[hh], kp[hh], 0.0f));
          lsum[hh] += p;
          ctx[hh]  += vp[hh] * p;
        }
      }
      float cx[DD];
      #pragma unroll
      for (int hh = 0; hh < NH; ++hh) {
        const float inv = rcp_fast(lsum[hh]);
        cx[2 * hh]     = ctx[hh].x * inv;
        cx[2 * hh + 1] = ctx[hh].y * inv;
      }
      #pragma unroll
      for (int od = 0; od < DD; ++od) {
        float acc = bol[od];
        #pragma unroll
        for (int d = 0; d < DD; ++d) acc += cx[d] * wo[od * DD + d];
        h[od] += acc;
      }
      lnorm16(h, g1, be1);
      float fv[FFD];
      #pragma unroll
      for (int f = 0; f < FFD; ++f) {
        float acc = b1l[f];
        #pragma unroll
        for (int d = 0; d < DD; ++d) acc += h[d] * w1[f * DD + d];
        fv[f] = fmaxf(acc, 0.f);
      }
      #pragma unroll
      for (int od = 0; od < DD; ++od) {
        float acc = b2l[od];
        #pragma unroll
        for (int f = 0; f < FFD; ++f) acc += fv[f] * w2[od * FFD + f];
        h[od] += acc;
      }
      lnorm16(h, g2, be2);
    }
  }

  __syncthreads();
  if (act && r == 0) {
    lnorm16(h, lnf_g, lnf_b);
    #pragma unroll
    for (int d = 0; d < DD; ++d) s_cls[j][d] = h[d];
  }
  __syncthreads();
  if (tid < FB_NBATCH * NP) {
    const int jj = tid / NP;
    const int oo = tid - jj * NP;
    if (blockIdx.x * FB_NBATCH + jj < B) {
      float acc = end_b[oo];
      #pragma unroll
      for (int d = 0; d < DD; ++d) acc += s_cls[jj][d] * end_w[oo * DD + d];
      s_lat[jj][oo] = acc * head_w[oo];
    }
  }
  __syncthreads();
  if (tid < FB_NBATCH) {
    const int bb = blockIdx.x * FB_NBATCH + tid;
    if (bb < B) {
      float acc = head_b[0];
      for (int o = 0; o < NP; ++o) acc += s_lat[tid][o];
      out[bb] = rcp_fast(1.f + exp2_fast(-acc * 1.4426950408889634f));
    }
  }
}

extern "C" void kernel_launch(void* const* d_in, const int* in_sizes, int n_in,
                              void* d_out, int out_size, void* d_ws, size_t ws_size,
                              hipStream_t stream) {
  const float* x       = (const float*)d_in[0];
  const float* conv_w  = (const float*)d_in[1];
  const float* conv_b  = (const float*)d_in[2];
  const float* cls_emb = (const float*)d_in[3];
  const float* Wqkv    = (const float*)d_in[4];
  const float* bqkv    = (const float*)d_in[5];
  const float* Wo      = (const float*)d_in[6];
  const float* bo      = (const float*)d_in[7];
  const float* W1      = (const float*)d_in[8];
  const float* b1      = (const float*)d_in[9];
  const float* W2      = (const float*)d_in[10];
  const float* b2      = (const float*)d_in[11];
  const float* ln1_g   = (const float*)d_in[12];
  const float* ln1_b   = (const float*)d_in[13];
  const float* ln2_g   = (const float*)d_in[14];
  const float* ln2_b   = (const float*)d_in[15];
  const float* lnf_g   = (const float*)d_in[16];
  const float* lnf_b   = (const float*)d_in[17];
  const float* end_w   = (const float*)d_in[18];
  const float* end_b   = (const float*)d_in[19];
  const float* head_w  = (const float*)d_in[20];
  const float* head_b  = (const float*)d_in[21];
  float* out = (float*)d_out;

  const int B = in_sizes[0] / SEQ;   // 2048

  if (ws_size >= NWPAIR * sizeof(unsigned)) {
    unsigned* wpk = (unsigned*)d_ws;
    pack_weights<<<(NWPAIR + 255) / 256, 256, 0, stream>>>(Wqkv, Wo, W1, W2, wpk);
    const int nb = (B + NBATCH - 1) / NBATCH;   // 1024
    transformer_fwd_g<<<nb, NT, 0, stream>>>(
        x, conv_w, conv_b, cls_emb, bqkv, bo, b1, b2,
        ln1_g, ln1_b, ln2_g, ln2_b, lnf_g, lnf_b, end_w, end_b, head_w, head_b,
        out, wpk, B);
  } else {
    const int nb = (B + FB_NBATCH - 1) / FB_NBATCH;
    transformer_fwd_lds<<<nb, FB_NT, 0, stream>>>(
        x, conv_w, conv_b, cls_emb, Wqkv, bqkv, Wo, bo, W1, b1, W2, b2,
        ln1_g, ln1_b, ln2_g, ln2_b, lnf_g, lnf_b, end_w, end_b, head_w, head_b,
        out, B);
  }
}